// Round 1
// baseline (469.405 us; speedup 1.0000x reference)
//
#include <hip/hip_runtime.h>

// EGNN_20744692040307 — algebraic collapse:
//   alpha = outer(v,v)/S is rank-1; v = first 32 rows of normalized Ep;
//   S ≈ 8192 exactly (each normalized row sums to 1; error ~1e-9 on alpha).
//   out[i,:] = softmax(v_i/S * (W @ (X^T v)) + b).
// So we never form Ep beyond its first 32 rows and never read 255/256 of E.

#define LEAKY 0.01f
constexpr float INV_S = 1.0f / 8192.0f;

// ---- kernel A: s = sum(Ai) + sum(Aj) -------------------------------------
__global__ __launch_bounds__(256) void k_scalar(const float* __restrict__ Ai,
                                                const float* __restrict__ Aj,
                                                float* __restrict__ s_out) {
    int t = threadIdx.x;
    float val = (t < 128) ? Ai[t] : Aj[t - 128];
    __shared__ float red[256];
    red[t] = val;
    __syncthreads();
    for (int off = 128; off > 0; off >>= 1) {
        if (t < off) red[t] += red[t + off];
        __syncthreads();
    }
    if (t == 0) s_out[0] = red[0];
}

// ---- kernel B: g = exp(leakyrelu(s*(X @ W^T + b)))  (8192x256) -----------
// 512 blocks x 16 rows; thread = output column k. X tile staged in LDS
// (uniform broadcast reads); W row per thread via float4 (L1-resident).
__global__ __launch_bounds__(256) void k_g(const float* __restrict__ X,
                                           const float* __restrict__ W,
                                           const float* __restrict__ b,
                                           const float* __restrict__ s_ptr,
                                           float* __restrict__ g) {
    __shared__ float4 Xs[16 * 32];  // 16 rows x 128 floats
    int tid = threadIdx.x;
    int row0 = blockIdx.x * 16;
    const float4* X4 = (const float4*)(X + (size_t)row0 * 128);
    Xs[tid] = X4[tid];
    Xs[tid + 256] = X4[tid + 256];
    __syncthreads();

    float s = s_ptr[0];
    float bk = b[tid];
    const float4* W4 = (const float4*)(W + (size_t)tid * 128);

    float acc[16];
#pragma unroll
    for (int r = 0; r < 16; r++) acc[r] = 0.f;

    for (int c4 = 0; c4 < 32; c4++) {
        float4 w = W4[c4];
#pragma unroll
        for (int r = 0; r < 16; r++) {
            float4 x = Xs[r * 32 + c4];
            acc[r] += w.x * x.x + w.y * x.y + w.z * x.z + w.w * x.w;
        }
    }
#pragma unroll
    for (int r = 0; r < 16; r++) {
        float a = s * (acc[r] + bk);
        float lr = (a >= 0.f) ? a : LEAKY * a;
        g[(size_t)(row0 + r) * 256 + tid] = expf(lr);
    }
}

// ---- kernel C: Ep_top partials: part[j][p][k] = sum_{m in chunk p} E[j,m]*g[m,k]
// grid (16 p-chunks, 8 j-groups of 4). chunk = 512 m.
__global__ __launch_bounds__(256) void k_ep(const float* __restrict__ E,
                                            const float* __restrict__ g,
                                            float* __restrict__ part) {
    int k = threadIdx.x;
    int p = blockIdx.x;   // 0..15
    int jg = blockIdx.y;  // 0..7
    int j0 = jg * 4;
    int m0 = p * 512;
    const float* E0 = E + (size_t)(j0 + 0) * 8192;
    const float* E1 = E + (size_t)(j0 + 1) * 8192;
    const float* E2 = E + (size_t)(j0 + 2) * 8192;
    const float* E3 = E + (size_t)(j0 + 3) * 8192;
    float a0 = 0.f, a1 = 0.f, a2 = 0.f, a3 = 0.f;
    for (int m = m0; m < m0 + 512; m++) {
        float gv = g[(size_t)m * 256 + k];
        a0 += E0[m] * gv;
        a1 += E1[m] * gv;
        a2 += E2[m] * gv;
        a3 += E3[m] * gv;
    }
    part[(size_t)((j0 + 0) * 16 + p) * 256 + k] = a0;
    part[(size_t)((j0 + 1) * 16 + p) * 256 + k] = a1;
    part[(size_t)((j0 + 2) * 16 + p) * 256 + k] = a2;
    part[(size_t)((j0 + 3) * 16 + p) * 256 + k] = a3;
}

// ---- kernel D: v[j*256+k] = Ep[j,k] / rowsum_j, j in [0,32) --------------
__global__ __launch_bounds__(256) void k_v(const float* __restrict__ part,
                                           float* __restrict__ v) {
    int k = threadIdx.x;
    int j = blockIdx.x;
    float ep = 0.f;
#pragma unroll
    for (int p = 0; p < 16; p++) ep += part[(size_t)(j * 16 + p) * 256 + k];

    float w = ep;
    for (int off = 32; off > 0; off >>= 1) w += __shfl_down(w, off, 64);
    __shared__ float red[4];
    if ((k & 63) == 0) red[k >> 6] = w;
    __syncthreads();
    float r = red[0] + red[1] + red[2] + red[3];
    v[(size_t)j * 256 + k] = ep / r;
}

// ---- kernel E: u-partials: upart[blk][c] = sum over 128 rows of v[i]*X[i,c]
__global__ __launch_bounds__(256) void k_u(const float* __restrict__ X,
                                           const float* __restrict__ v,
                                           float* __restrict__ upart) {
    int tid = threadIdx.x;
    int c = tid & 127;
    int h = tid >> 7;  // 0/1
    int i0 = blockIdx.x * 128 + h * 64;
    float acc = 0.f;
    for (int t = 0; t < 64; t++) {
        int i = i0 + t;
        acc += v[i] * X[(size_t)i * 128 + c];
    }
    __shared__ float red[256];
    red[tid] = acc;
    __syncthreads();
    if (tid < 128) upart[(size_t)blockIdx.x * 128 + tid] = red[tid] + red[tid + 128];
}

// ---- kernel F2: y = W @ u  (u reduced from 64 partials) ------------------
__global__ __launch_bounds__(256) void k_y(const float* __restrict__ upart,
                                           const float* __restrict__ W,
                                           float* __restrict__ y) {
    __shared__ float u[128];
    int k = threadIdx.x;
    if (k < 128) {
        float a = 0.f;
        for (int bb = 0; bb < 64; bb++) a += upart[(size_t)bb * 128 + k];
        u[k] = a;
    }
    __syncthreads();
    float acc = 0.f;
    for (int c = 0; c < 128; c++) acc += W[(size_t)k * 128 + c] * u[c];
    y[k] = acc;
}

// ---- kernel F: out[i,:] = softmax(v[i]*INV_S*y + b), 4 rows/block --------
__global__ __launch_bounds__(256) void k_out(const float* __restrict__ v,
                                             const float* __restrict__ y,
                                             const float* __restrict__ b,
                                             float* __restrict__ out) {
    int k = threadIdx.x;
    float yk = y[k];
    float bk = b[k];
    __shared__ float red[4];
    for (int rr = 0; rr < 4; rr++) {
        int i = blockIdx.x * 4 + rr;
        float z = v[i] * INV_S * yk + bk;
        float m = z;
        for (int off = 32; off > 0; off >>= 1) m = fmaxf(m, __shfl_down(m, off, 64));
        if ((k & 63) == 0) red[k >> 6] = m;
        __syncthreads();
        m = fmaxf(fmaxf(red[0], red[1]), fmaxf(red[2], red[3]));
        __syncthreads();
        float e = expf(z - m);
        float ssum = e;
        for (int off = 32; off > 0; off >>= 1) ssum += __shfl_down(ssum, off, 64);
        if ((k & 63) == 0) red[k >> 6] = ssum;
        __syncthreads();
        ssum = red[0] + red[1] + red[2] + red[3];
        out[(size_t)i * 256 + k] = e / ssum;
        __syncthreads();
    }
}

// ---- kernel G: alpha[i,j] = v[i]*v[j]*INV_S  (256 MB write-bound) --------
// 2048 blocks x 4 rows; v chunk held in registers as 8 float4 per thread.
__global__ __launch_bounds__(256) void k_alpha(const float* __restrict__ v,
                                               float* __restrict__ alpha) {
    int tid = threadIdx.x;
    const float4* v4 = (const float4*)v;
    float4 vv[8];
#pragma unroll
    for (int jj = 0; jj < 8; jj++) vv[jj] = v4[tid + jj * 256];
#pragma unroll
    for (int rr = 0; rr < 4; rr++) {
        int i = blockIdx.x * 4 + rr;
        float sc = v[i] * INV_S;
        float4* A4 = (float4*)(alpha + (size_t)i * 8192);
#pragma unroll
        for (int jj = 0; jj < 8; jj++) {
            float4 t = vv[jj];
            A4[tid + jj * 256] = make_float4(t.x * sc, t.y * sc, t.z * sc, t.w * sc);
        }
    }
}

extern "C" void kernel_launch(void* const* d_in, const int* in_sizes, int n_in,
                              void* d_out, int out_size, void* d_ws, size_t ws_size,
                              hipStream_t stream) {
    const float* X  = (const float*)d_in[0];  // 8192 x 128
    const float* E  = (const float*)d_in[1];  // 8192 x 8192
    const float* W  = (const float*)d_in[2];  // 256 x 128
    const float* b  = (const float*)d_in[3];  // 256
    const float* Ai = (const float*)d_in[4];  // 128
    const float* Aj = (const float*)d_in[5];  // 128

    float* out   = (float*)d_out;             // 8192*256
    float* alpha = out + 2097152;             // 8192*8192

    float* ws    = (float*)d_ws;
    float* s_    = ws;                        // 1 (pad to 256)
    float* g     = ws + 256;                  // 2097152
    float* part  = g + 2097152;               // 32*16*256 = 131072
    float* v     = part + 131072;             // 8192
    float* upart = v + 8192;                  // 64*128 = 8192
    float* y     = upart + 8192;              // 256

    k_scalar<<<1, 256, 0, stream>>>(Ai, Aj, s_);
    k_g<<<512, 256, 0, stream>>>(X, W, b, s_, g);
    k_ep<<<dim3(16, 8), 256, 0, stream>>>(E, g, part);
    k_v<<<32, 256, 0, stream>>>(part, v);
    k_u<<<64, 256, 0, stream>>>(X, v, upart);
    k_y<<<1, 256, 0, stream>>>(upart, W, y);
    k_out<<<2048, 256, 0, stream>>>(v, y, b, out);
    k_alpha<<<2048, 256, 0, stream>>>(v, alpha);
}